// Round 1
// baseline (510.596 us; speedup 1.0000x reference)
//
#include <hip/hip_runtime.h>

// Batched symmetric matrix exponential via scaling-and-squaring.
// X: [B,32,32] fp32 symmetric. Y = expm(X) = V diag(exp(s)) V^T.
// One wave (64 threads) per matrix; per-lane 4x4 register tile for the
// 32x32x32 matmuls; LDS rows padded to 36 floats (144 B, 16B-aligned so
// float4 ds_read_b128 works; bank spread ok).

#define LDS_STRIDE 36

__global__ __launch_bounds__(64) void expm32_kernel(const float* __restrict__ X,
                                                    float* __restrict__ Y) {
    __shared__ float A[32][LDS_STRIDE];  // scaled input
    __shared__ float P[32][LDS_STRIDE];  // polynomial / running power

    const int b = blockIdx.x;
    const int t = threadIdx.x;  // 0..63
    const float* Xb = X + (size_t)b * 1024;
    float*       Yb = Y + (size_t)b * 1024;

    // ---- load 1024 floats (16/thread, float4 coalesced) ----
#pragma unroll
    for (int j = 0; j < 4; ++j) {
        int v = j * 64 + t;           // float4 index 0..255
        float4 val = ((const float4*)Xb)[v];
        int flat = v * 4;
        int r = flat >> 5, c = flat & 31;
        *(float4*)&A[r][c] = val;
    }
    __syncthreads();

    // ---- inf-norm (max row abs-sum) ----
    const int rn = t & 31, hn = t >> 5;
    float sum = 0.f;
#pragma unroll
    for (int c = 0; c < 16; ++c) sum += fabsf(A[rn][hn * 16 + c]);
    sum += __shfl_xor(sum, 32);
    float nrm = sum;
#pragma unroll
    for (int m = 16; m >= 1; m >>= 1) nrm = fmaxf(nrm, __shfl_xor(nrm, m));

    // ---- choose s so that ||A|| * 2^-s <= 0.5 ----
    int s = 0;
    float scale = 1.f;
    while (nrm * scale > 0.5f && s < 40) { scale *= 0.5f; ++s; }

    // scale A in place (each lane owns the same row-half it summed)
#pragma unroll
    for (int c = 0; c < 16; ++c) A[rn][hn * 16 + c] *= scale;

    // ---- P = I + A/8  (degree-8 Taylor, Horner init) ----
#pragma unroll
    for (int c = 0; c < 16; ++c) {
        int cc = hn * 16 + c;
        P[rn][cc] = A[rn][cc] * 0.125f + ((rn == cc) ? 1.f : 0.f);
    }
    __syncthreads();

    const int ti = t >> 3, tj = t & 7;
    const int r0 = ti * 4, c0 = tj * 4;

    float acc[4][4];

    // matmul core: acc = L(rows r0..r0+3) * R(cols c0..c0+3), full K=32
#define MM_CORE(Lm, Rm)                                                       \
    {                                                                         \
        _Pragma("unroll") for (int rr = 0; rr < 4; ++rr)                      \
            _Pragma("unroll") for (int cc = 0; cc < 4; ++cc) acc[rr][cc] = 0.f;\
        _Pragma("unroll") for (int kb = 0; kb < 8; ++kb) {                    \
            float4 av[4], bv[4];                                              \
            _Pragma("unroll") for (int rr = 0; rr < 4; ++rr)                  \
                av[rr] = *(const float4*)&Lm[r0 + rr][kb * 4];                \
            _Pragma("unroll") for (int kk = 0; kk < 4; ++kk)                  \
                bv[kk] = *(const float4*)&Rm[kb * 4 + kk][c0];                \
            _Pragma("unroll") for (int rr = 0; rr < 4; ++rr) {                \
                float al[4] = {av[rr].x, av[rr].y, av[rr].z, av[rr].w};       \
                _Pragma("unroll") for (int kk = 0; kk < 4; ++kk) {            \
                    acc[rr][0] += al[kk] * bv[kk].x;                          \
                    acc[rr][1] += al[kk] * bv[kk].y;                          \
                    acc[rr][2] += al[kk] * bv[kk].z;                          \
                    acc[rr][3] += al[kk] * bv[kk].w;                          \
                }                                                             \
            }                                                                 \
        }                                                                     \
    }

    // ---- Horner: for j = 7..1:  P = I + (A*P)/j ----
    for (int j = 7; j >= 1; --j) {
        MM_CORE(A, P);
        __syncthreads();
        float invj = 1.f / (float)j;
#pragma unroll
        for (int rr = 0; rr < 4; ++rr)
#pragma unroll
            for (int cc = 0; cc < 4; ++cc) {
                int gr = r0 + rr, gc = c0 + cc;
                P[gr][gc] = acc[rr][cc] * invj + ((gr == gc) ? 1.f : 0.f);
            }
        __syncthreads();
    }

    // ---- s squarings: P = P*P ----
    for (int q = 0; q < s; ++q) {
        MM_CORE(P, P);
        __syncthreads();
#pragma unroll
        for (int rr = 0; rr < 4; ++rr)
#pragma unroll
            for (int cc = 0; cc < 4; ++cc)
                P[r0 + rr][c0 + cc] = acc[rr][cc];
        __syncthreads();
    }

    // ---- store (float4 coalesced) ----
#pragma unroll
    for (int j = 0; j < 4; ++j) {
        int v = j * 64 + t;
        int flat = v * 4;
        int r = flat >> 5, c = flat & 31;
        ((float4*)Yb)[v] = *(float4*)&P[r][c];
    }
#undef MM_CORE
}

extern "C" void kernel_launch(void* const* d_in, const int* in_sizes, int n_in,
                              void* d_out, int out_size, void* d_ws, size_t ws_size,
                              hipStream_t stream) {
    const float* x = (const float*)d_in[0];
    float* y = (float*)d_out;
    int B = in_sizes[0] / 1024;  // 32768 matrices of 32x32
    expm32_kernel<<<B, 64, 0, stream>>>(x, y);
}

// Round 2
// 281.897 us; speedup vs baseline: 1.8113x; 1.8113x over previous
//
#include <hip/hip_runtime.h>

// Batched symmetric matrix exponential, split-bf16 MFMA version.
// X: [B,32,32] fp32 symmetric. Y = expm(X).
// One wave per matrix. Scaling-and-squaring: s = ceil-ish(log2(||A||inf/0.5)),
// degree-8 Taylor via Horner on A*2^-s, then s squarings.
// Each 32x32x32 fp32 matmul is done as 3 split-bf16 products (hi*hi, hi*lo,
// lo*hi) = 6 v_mfma_f32_32x32x16_bf16. All iterates are symmetric polynomials
// of A, so one fragment set serves both MFMA operands, and the C/D output is
// re-chained into A/B fragment layout with 16 ds_bpermute(lane^32) + cndmask
// (no LDS arrays at all).
//
// Layouts (gfx950, guide-verified):
//   C/D: col = lane&31, row = (reg&3) + 8*(reg>>2) + 4*(lane>>5)
//   A:   m = lane&31,   k = 8*(lane>>5) + j   (j = 0..7, two K-halves per matmul)
//   B:   n = lane&31,   k = 8*(lane>>5) + j   (operand symmetric => same regs)

typedef __attribute__((ext_vector_type(8))) short short8;
typedef __attribute__((ext_vector_type(16))) float f32x16;

union PackAB { unsigned int u[4]; short8 v; };

// round-to-nearest-even bf16, returned as fp32 bit pattern with low 16 zero
__device__ __forceinline__ unsigned rne_hi_bits(float x) {
    unsigned u = __float_as_uint(x);
    return (u + 0x7fffu + ((u >> 16) & 1u)) & 0xffff0000u;
}

// pack two bf16-valued fp32 (top 16 bits) into one dword: {lo=x0, hi=x1}
__device__ __forceinline__ unsigned pack_pair(unsigned u0, unsigned u1) {
    return __builtin_amdgcn_perm(u1, u0, 0x07060302u);
}

__global__ __launch_bounds__(64) void expm32_mfma(const float* __restrict__ X,
                                                  float* __restrict__ Y) {
    const int t = threadIdx.x;
    const int m = t & 31;          // our row (A) / col (C)
    const bool hb = (t >= 32);     // lane half
    const int h8 = hb ? 8 : 0;
    const int paddr = (t ^ 32) << 2;  // ds_bpermute byte address of partner lane

    // ---- load our 16 elements directly in A-fragment order ----
    // a[f*8+j] = X[m][16f + 8h + j];  wave covers the 4KB matrix densely.
    const float* Xb = X + (size_t)blockIdx.x * 1024 + m * 32 + h8;
    float4 q00 = *(const float4*)(Xb + 0);
    float4 q01 = *(const float4*)(Xb + 4);
    float4 q10 = *(const float4*)(Xb + 16);
    float4 q11 = *(const float4*)(Xb + 20);
    float a[16] = {q00.x, q00.y, q00.z, q00.w, q01.x, q01.y, q01.z, q01.w,
                   q10.x, q10.y, q10.z, q10.w, q11.x, q11.y, q11.z, q11.w};

    // ---- inf-norm: own half-row + partner half-row, then max over rows ----
    float ssum = 0.f;
#pragma unroll
    for (int i = 0; i < 16; ++i) ssum += fabsf(a[i]);
    ssum += __shfl_xor(ssum, 32);
    float nrm = ssum;
#pragma unroll
    for (int w = 16; w >= 1; w >>= 1) nrm = fmaxf(nrm, __shfl_xor(nrm, w));

    int s = 0;
    float nn = nrm;
    while (nn > 0.5f && s < 48) { nn *= 0.5f; ++s; }
    const float scale = ldexpf(1.0f, -s);
#pragma unroll
    for (int i = 0; i < 16; ++i) a[i] *= scale;

    PackAB ah[2], al[2], ph[2], pl[2];

    // ---- split A into bf16 hi/lo frags (already in frag order) ----
#pragma unroll
    for (int i = 0; i < 8; ++i) {
        unsigned uh0 = rne_hi_bits(a[2 * i]);
        unsigned uh1 = rne_hi_bits(a[2 * i + 1]);
        float l0 = a[2 * i] - __uint_as_float(uh0);
        float l1 = a[2 * i + 1] - __uint_as_float(uh1);
        ah[i >> 2].u[i & 3] = pack_pair(uh0, uh1);
        al[i >> 2].u[i & 3] = pack_pair(__float_as_uint(l0), __float_as_uint(l1));
    }

    // ---- P0 = I + A/8 (frag order), split ----
    float pf[16];
#pragma unroll
    for (int i = 0; i < 16; ++i) {
        int k = ((i >> 3) << 4) + h8 + (i & 7);
        pf[i] = 0.125f * a[i] + ((k == m) ? 1.f : 0.f);
    }
#pragma unroll
    for (int i = 0; i < 8; ++i) {
        unsigned uh0 = rne_hi_bits(pf[2 * i]);
        unsigned uh1 = rne_hi_bits(pf[2 * i + 1]);
        float l0 = pf[2 * i] - __uint_as_float(uh0);
        float l1 = pf[2 * i + 1] - __uint_as_float(uh1);
        ph[i >> 2].u[i & 3] = pack_pair(uh0, uh1);
        pl[i >> 2].u[i & 3] = pack_pair(__float_as_uint(l0), __float_as_uint(l1));
    }

    // diag mask per C-reg (for folding +j*I into the accumulator init)
    bool dg[16];
#pragma unroll
    for (int r = 0; r < 16; ++r) {
        int row = (r & 3) + 8 * (r >> 2) + (hb ? 4 : 0);
        dg[r] = (row == m);
    }

    float c[16];  // result in C-layout

    // chain: c (C-layout, symmetric matrix) -> ph/pl fragments for next matmul
    auto chain = [&]() {
        unsigned ch[8], cl8[8];
#pragma unroll
        for (int i = 0; i < 8; ++i) {
            unsigned uh0 = rne_hi_bits(c[2 * i]);
            unsigned uh1 = rne_hi_bits(c[2 * i + 1]);
            float l0 = c[2 * i] - __uint_as_float(uh0);
            float l1 = c[2 * i + 1] - __uint_as_float(uh1);
            ch[i] = pack_pair(uh0, uh1);
            cl8[i] = pack_pair(__float_as_uint(l0), __float_as_uint(l1));
        }
        unsigned ech[8], ecl[8];
#pragma unroll
        for (int i = 0; i < 8; ++i) {
            ech[i] = (unsigned)__builtin_amdgcn_ds_bpermute(paddr, (int)ch[i]);
            ecl[i] = (unsigned)__builtin_amdgcn_ds_bpermute(paddr, (int)cl8[i]);
        }
        ph[0].u[0] = hb ? ech[2] : ch[0];
        ph[0].u[1] = hb ? ech[3] : ch[1];
        ph[0].u[2] = hb ? ch[2] : ech[0];
        ph[0].u[3] = hb ? ch[3] : ech[1];
        ph[1].u[0] = hb ? ech[6] : ch[4];
        ph[1].u[1] = hb ? ech[7] : ch[5];
        ph[1].u[2] = hb ? ch[6] : ech[4];
        ph[1].u[3] = hb ? ch[7] : ech[5];
        pl[0].u[0] = hb ? ecl[2] : cl8[0];
        pl[0].u[1] = hb ? ecl[3] : cl8[1];
        pl[0].u[2] = hb ? cl8[2] : ecl[0];
        pl[0].u[3] = hb ? cl8[3] : ecl[1];
        pl[1].u[0] = hb ? ecl[6] : cl8[4];
        pl[1].u[1] = hb ? ecl[7] : cl8[5];
        pl[1].u[2] = hb ? cl8[6] : ecl[4];
        pl[1].u[3] = hb ? cl8[7] : ecl[5];
    };

    auto mm6 = [&](PackAB* Ah, PackAB* Al, PackAB* Bh, PackAB* Bl, f32x16 d) {
        d = __builtin_amdgcn_mfma_f32_32x32x16_bf16(Ah[0].v, Bh[0].v, d, 0, 0, 0);
        d = __builtin_amdgcn_mfma_f32_32x32x16_bf16(Ah[1].v, Bh[1].v, d, 0, 0, 0);
        d = __builtin_amdgcn_mfma_f32_32x32x16_bf16(Ah[0].v, Bl[0].v, d, 0, 0, 0);
        d = __builtin_amdgcn_mfma_f32_32x32x16_bf16(Ah[1].v, Bl[1].v, d, 0, 0, 0);
        d = __builtin_amdgcn_mfma_f32_32x32x16_bf16(Al[0].v, Bh[0].v, d, 0, 0, 0);
        d = __builtin_amdgcn_mfma_f32_32x32x16_bf16(Al[1].v, Bh[1].v, d, 0, 0, 0);
        return d;
    };

    // ---- Horner: P <- I + (A*P)/j, j = 7..1  (jI folded into acc init) ----
#pragma unroll
    for (int j = 7; j >= 1; --j) {
        const float jf = (float)j;
        f32x16 acc;
#pragma unroll
        for (int r = 0; r < 16; ++r) acc[r] = dg[r] ? jf : 0.f;
        acc = mm6(ah, al, ph, pl, acc);
        const float invj = 1.f / jf;
#pragma unroll
        for (int r = 0; r < 16; ++r) c[r] = acc[r] * invj;
        if (j > 1 || s > 0) chain();
    }

    // ---- s squarings: P <- P*P ----
    for (int q = 0; q < s; ++q) {
        f32x16 acc;
#pragma unroll
        for (int r = 0; r < 16; ++r) acc[r] = 0.f;
        acc = mm6(ph, pl, ph, pl, acc);
#pragma unroll
        for (int r = 0; r < 16; ++r) c[r] = acc[r];
        if (q < s - 1) chain();
    }

    // ---- store from C-layout, coalesced per 32-lane half ----
    float* Yb = Y + (size_t)blockIdx.x * 1024 + m + (hb ? 128 : 0);
#pragma unroll
    for (int r = 0; r < 16; ++r) {
        int rowbase = (r & 3) + 8 * (r >> 2);
        Yb[rowbase * 32] = c[r];
    }
}

extern "C" void kernel_launch(void* const* d_in, const int* in_sizes, int n_in,
                              void* d_out, int out_size, void* d_ws, size_t ws_size,
                              hipStream_t stream) {
    const float* x = (const float*)d_in[0];
    float* y = (float*)d_out;
    int B = in_sizes[0] / 1024;
    expm32_mfma<<<B, 64, 0, stream>>>(x, y);
}

// Round 4
// 228.319 us; speedup vs baseline: 2.2363x; 1.2347x over previous
//
#include <hip/hip_runtime.h>

// Batched symmetric matrix exponential (fp32 32x32), MFMA-native layout.
//
// All iterates are symmetric polynomials of the symmetric input, and MFMA's
// contraction is permutation-invariant in k. We keep every matrix in the
// MFMA C/D register layout (lane holds column m = lane&31; reg r holds row
// rho(r) = (r&3) + 8*(r>>2) + 4*(lane>>5)) and feed those same registers back
// as A and B operands: the hardware then computes sum_rho M[rho][i]*M[rho][n]
// = (M^T M)[i][n] = (M*M)[i][n] for symmetric M. The two lane-halves' rho
// sets partition 0..31, so the contraction covers every k exactly once.
// => no layout conversion (no bpermute / cndmask chains) anywhere.
//
// fp32 precision is recovered by fp16 hi/lo splitting (v_cvt_pkrtz): each
// 32^3 fp32 matmul = hi*hi + hi*lo + lo*hi = 6 v_mfma_f32_32x32x16_f16.
//
// Algorithm: scaling-and-squaring, theta = 1.0, degree-8 Taylor via
// Paterson-Stockmeyer: P = (c0+c1*A+c2*A2+c3*A3) + (c4+c5*A+c6*A2+c7*A3+c8*A4)*A4
// (4 matmuls: A2, A3, A4, U*A4), then s squarings (s = ceil(log2(||A||inf))).

typedef _Float16 f16x8 __attribute__((ext_vector_type(8)));
typedef __fp16 hf2 __attribute__((ext_vector_type(2)));
typedef float f32x16 __attribute__((ext_vector_type(16)));

union Frag { unsigned u[4]; f16x8 v; };

__device__ __forceinline__ void split_pair(float x0, float x1,
                                           unsigned& uh, unsigned& ul) {
    hf2 h = __builtin_amdgcn_cvt_pkrtz(x0, x1);   // rtz; lo captures residue
    float h0 = (float)h[0], h1 = (float)h[1];
    hf2 l = __builtin_amdgcn_cvt_pkrtz(x0 - h0, x1 - h1);
    uh = __builtin_bit_cast(unsigned, h);
    ul = __builtin_bit_cast(unsigned, l);
}

__device__ __forceinline__ void split16(const float* c, Frag* fh, Frag* fl) {
#pragma unroll
    for (int i = 0; i < 8; ++i)
        split_pair(c[2 * i], c[2 * i + 1], fh[i >> 2].u[i & 3], fl[i >> 2].u[i & 3]);
}

__device__ __forceinline__ f32x16 mm6(const Frag* Ah, const Frag* Al,
                                      const Frag* Bh, const Frag* Bl, f32x16 d) {
    d = __builtin_amdgcn_mfma_f32_32x32x16_f16(Ah[0].v, Bh[0].v, d, 0, 0, 0);
    d = __builtin_amdgcn_mfma_f32_32x32x16_f16(Ah[1].v, Bh[1].v, d, 0, 0, 0);
    d = __builtin_amdgcn_mfma_f32_32x32x16_f16(Ah[0].v, Bl[0].v, d, 0, 0, 0);
    d = __builtin_amdgcn_mfma_f32_32x32x16_f16(Ah[1].v, Bl[1].v, d, 0, 0, 0);
    d = __builtin_amdgcn_mfma_f32_32x32x16_f16(Al[0].v, Bh[0].v, d, 0, 0, 0);
    d = __builtin_amdgcn_mfma_f32_32x32x16_f16(Al[1].v, Bh[1].v, d, 0, 0, 0);
    return d;
}

#define WPB 4  // waves (matrices) per block; lifts the ~16 wg/CU cap

__global__ __launch_bounds__(64 * WPB) void expm32_v3(const float* __restrict__ X,
                                                      float* __restrict__ Y) {
    const int t = threadIdx.x & 63;
    const int w = threadIdx.x >> 6;
    const size_t mat = (size_t)blockIdx.x * WPB + w;
    const int m = t & 31;
    const int hb4 = (t >> 5) * 4;

    // load directly in C/D order: a[r] = X[m][rho(r)], rho(r)=(r&3)+8*(r>>2)+hb4
    const float* Xb = X + mat * 1024 + m * 32 + hb4;
    float4 q0 = *(const float4*)(Xb + 0);
    float4 q1 = *(const float4*)(Xb + 8);
    float4 q2 = *(const float4*)(Xb + 16);
    float4 q3 = *(const float4*)(Xb + 24);
    float a[16] = {q0.x, q0.y, q0.z, q0.w, q1.x, q1.y, q1.z, q1.w,
                   q2.x, q2.y, q2.z, q2.w, q3.x, q3.y, q3.z, q3.w};

    // inf-norm: half-row sum + partner half, max over rows
    float ssum = 0.f;
#pragma unroll
    for (int i = 0; i < 16; ++i) ssum += fabsf(a[i]);
    ssum += __shfl_xor(ssum, 32);
    float nrm = ssum;
#pragma unroll
    for (int d = 16; d >= 1; d >>= 1) nrm = fmaxf(nrm, __shfl_xor(nrm, d));

    int s = 0;
    float nn = nrm;
    while (nn > 1.0f && s < 40) { nn *= 0.5f; ++s; }
    const float scale = __int_as_float((127 - s) << 23);  // exact 2^-s
#pragma unroll
    for (int i = 0; i < 16; ++i) a[i] *= scale;

    // diagonal indicator per C-slot
    float dgm[16];
#pragma unroll
    for (int r = 0; r < 16; ++r) {
        int rho = (r & 3) + 8 * (r >> 2) + hb4;
        dgm[r] = (rho == m) ? 1.f : 0.f;
    }

    const float c2 = 0.5f, c3 = 1.f / 6.f, c4 = 1.f / 24.f, c5 = 1.f / 120.f,
                c6 = 1.f / 720.f, c7 = 1.f / 5040.f, c8 = 1.f / 40320.f;

    float U[16], W[16];
#pragma unroll
    for (int r = 0; r < 16; ++r) {
        U[r] = c4 * dgm[r] + c5 * a[r];
        W[r] = dgm[r] + a[r];
    }

    Frag ah[2], al[2], bh[2], bl[2], fh[2], fl[2];
    split16(a, ah, al);

    f32x16 z;
#pragma unroll
    for (int r = 0; r < 16; ++r) z[r] = 0.f;

    float cc[16];

    // A2 = A*A
    f32x16 acc = mm6(ah, al, ah, al, z);
#pragma unroll
    for (int r = 0; r < 16; ++r) {
        cc[r] = acc[r];
        U[r] += c6 * cc[r];
        W[r] += c2 * cc[r];
    }
    split16(cc, bh, bl);  // A2 frags

    // A3 = A*A2 (additive only; no split needed)
    acc = mm6(ah, al, bh, bl, z);
#pragma unroll
    for (int r = 0; r < 16; ++r) {
        U[r] += c7 * acc[r];
        W[r] += c3 * acc[r];
    }

    // A4 = A2*A2
    acc = mm6(bh, bl, bh, bl, z);
#pragma unroll
    for (int r = 0; r < 16; ++r) {
        cc[r] = acc[r];
        U[r] += c8 * cc[r];
    }
    split16(cc, fh, fl);  // A4 frags

    split16(U, ah, al);   // U frags (A frags dead)

    // P = U*A4 + W  (W folded into accumulator init)
    f32x16 accw;
#pragma unroll
    for (int r = 0; r < 16; ++r) accw[r] = W[r];
    acc = mm6(ah, al, fh, fl, accw);
#pragma unroll
    for (int r = 0; r < 16; ++r) cc[r] = acc[r];

    // s squarings, all in C/D layout
    for (int q = 0; q < s; ++q) {
        split16(cc, ah, al);
        acc = mm6(ah, al, ah, al, z);
#pragma unroll
        for (int r = 0; r < 16; ++r) cc[r] = acc[r];
    }

    // store: lane m writes column m of 16 rows (coalesced across lanes)
    float* Yb = Y + mat * 1024 + m;
#pragma unroll
    for (int r = 0; r < 16; ++r) {
        int rho = (r & 3) + 8 * (r >> 2) + hb4;
        Yb[rho * 32] = cc[r];
    }
}

extern "C" void kernel_launch(void* const* d_in, const int* in_sizes, int n_in,
                              void* d_out, int out_size, void* d_ws, size_t ws_size,
                              hipStream_t stream) {
    const float* x = (const float*)d_in[0];
    float* y = (float*)d_out;
    int B = in_sizes[0] / 1024;
    expm32_v3<<<B / WPB, 64 * WPB, 0, stream>>>(x, y);
}

// Round 5
// 228.081 us; speedup vs baseline: 2.2387x; 1.0010x over previous
//
#include <hip/hip_runtime.h>

// Batched symmetric matrix exponential (fp32 32x32), MFMA-native layout, v4.
//
// Invariant trick: all iterates are symmetric polynomials of the symmetric
// input, and MFMA's k-contraction is permutation-invariant. Every matrix
// lives in the MFMA C/D register layout (lane holds column m = lane&31;
// reg r holds row rho(r) = (r&3) + 8*(r>>2) + 4*(lane>>5)). Feeding those
// same registers back as both A and B operands computes
// sum_rho M[rho][i]*M[rho][n] = (M^T M)[i][n] = (M*M)[i][n] for symmetric M
// (the two lane-halves' rho sets partition k = 0..31). No layout conversion
// anywhere. Empirically verified (R2/R3 passed, absmax 8).
//
// fp32 precision via fp16 hi/lo split (v_cvt_pkrtz): one 32^3 fp32 matmul =
// hh + hl + lh = 6 x v_mfma_f32_32x32x16_f16.
//
// v4 changes (codegen-targeted): no unions, no pointer-passed arrays —
// everything is value-typed ext-vectors (f32x16 / f16x8 via bit_cast of
// u32x4) so SROA keeps it all in registers; whole-vector U/W updates;
// 64-thread blocks (R1 showed better residency than 256-thr).
//
// Algorithm: scaling-and-squaring, theta = 1.0, degree-8 Taylor via
// Paterson-Stockmeyer: exp(A) ~= W + U*A4,
//   W = I + A + A2/2 + A3/6,  U = I/24 + A/120 + A2/720 + A3/5040 + A4/40320
// (4 matmuls: A2, A3, A4, U*A4), then s squarings, s = ceil(log2(||A||inf)).

typedef _Float16 f16x8 __attribute__((ext_vector_type(8)));
typedef __fp16 hf2 __attribute__((ext_vector_type(2)));
typedef float f32x16 __attribute__((ext_vector_type(16)));
typedef unsigned u32x4 __attribute__((ext_vector_type(4)));

struct Op { f16x8 h0, h1, l0, l1; };

__device__ __forceinline__ Op split(f32x16 mv) {
    unsigned uh[8], ul[8];
#pragma unroll
    for (int j = 0; j < 8; ++j) {
        float x0 = mv[2 * j], x1 = mv[2 * j + 1];
        hf2 h = __builtin_amdgcn_cvt_pkrtz(x0, x1);           // rtz hi
        hf2 l = __builtin_amdgcn_cvt_pkrtz(x0 - (float)h[0],  // exact residue
                                           x1 - (float)h[1]); // -> fp16 lo
        uh[j] = __builtin_bit_cast(unsigned, h);
        ul[j] = __builtin_bit_cast(unsigned, l);
    }
    Op o;
    o.h0 = __builtin_bit_cast(f16x8, (u32x4){uh[0], uh[1], uh[2], uh[3]});
    o.h1 = __builtin_bit_cast(f16x8, (u32x4){uh[4], uh[5], uh[6], uh[7]});
    o.l0 = __builtin_bit_cast(f16x8, (u32x4){ul[0], ul[1], ul[2], ul[3]});
    o.l1 = __builtin_bit_cast(f16x8, (u32x4){ul[4], ul[5], ul[6], ul[7]});
    return o;
}

__device__ __forceinline__ f32x16 mm6(Op a, Op b, f32x16 d) {
    d = __builtin_amdgcn_mfma_f32_32x32x16_f16(a.h0, b.h0, d, 0, 0, 0);
    d = __builtin_amdgcn_mfma_f32_32x32x16_f16(a.h1, b.h1, d, 0, 0, 0);
    d = __builtin_amdgcn_mfma_f32_32x32x16_f16(a.h0, b.l0, d, 0, 0, 0);
    d = __builtin_amdgcn_mfma_f32_32x32x16_f16(a.h1, b.l1, d, 0, 0, 0);
    d = __builtin_amdgcn_mfma_f32_32x32x16_f16(a.l0, b.h0, d, 0, 0, 0);
    d = __builtin_amdgcn_mfma_f32_32x32x16_f16(a.l1, b.h1, d, 0, 0, 0);
    return d;
}

__global__ __launch_bounds__(64) void expm32_v4(const float* __restrict__ X,
                                                float* __restrict__ Y) {
    const int t = threadIdx.x;
    const int m = t & 31;
    const int hb4 = (t >> 5) * 4;
    const size_t mat = blockIdx.x;

    // load in C/D order: A[r] = X[m][rho(r)], rho(r) = (r&3) + 8*(r>>2) + hb4
    const float* Xb = X + mat * 1024 + m * 32 + hb4;
    f32x16 A;
#pragma unroll
    for (int rq = 0; rq < 4; ++rq) {
        float4 q = *(const float4*)(Xb + rq * 8);
        A[4 * rq + 0] = q.x; A[4 * rq + 1] = q.y;
        A[4 * rq + 2] = q.z; A[4 * rq + 3] = q.w;
    }

    // inf-norm: own half-row sum + partner half, then max over rows
    float ssum = 0.f;
#pragma unroll
    for (int i = 0; i < 16; ++i) ssum += fabsf(A[i]);
    ssum += __shfl_xor(ssum, 32);
    float nrm = ssum;
#pragma unroll
    for (int d = 16; d >= 1; d >>= 1) nrm = fmaxf(nrm, __shfl_xor(nrm, d));

    int s = 0;
    float nn = nrm;
    while (nn > 1.0f && s < 40) { nn *= 0.5f; ++s; }
    const float scale = __int_as_float((127 - s) << 23);  // exact 2^-s
    A *= scale;

    // diagonal indicator in C/D layout
    f32x16 D;
#pragma unroll
    for (int r = 0; r < 16; ++r) {
        int rho = (r & 3) + 8 * (r >> 2) + hb4;
        D[r] = (rho == m) ? 1.f : 0.f;
    }

    const float c2 = 0.5f, c3 = 1.f / 6.f, c4 = 1.f / 24.f, c5 = 1.f / 120.f,
                c6 = 1.f / 720.f, c7 = 1.f / 5040.f, c8 = 1.f / 40320.f;

    f32x16 z{};  // zero accumulator

    Op oA = split(A);
    f32x16 A2 = mm6(oA, oA, z);

    f32x16 U = c4 * D + c5 * A + c6 * A2;
    f32x16 W = D + A + c2 * A2;

    Op oA2 = split(A2);
    f32x16 A3 = mm6(oA, oA2, z);
    U += c7 * A3;
    W += c3 * A3;

    f32x16 A4 = mm6(oA2, oA2, z);
    U += c8 * A4;

    Op oA4 = split(A4);
    Op oU = split(U);
    f32x16 P = mm6(oU, oA4, W);  // exp(A/2^s) ~= U*A4 + W

    for (int q = 0; q < s; ++q) {
        Op oP = split(P);
        P = mm6(oP, oP, z);
    }

    // store: lane m writes column m of 16 rows (contiguous across lanes)
    float* Yb = Y + mat * 1024 + m;
#pragma unroll
    for (int r = 0; r < 16; ++r) {
        int rho = (r & 3) + 8 * (r >> 2) + hb4;
        Yb[rho * 32] = P[r];
    }
}

extern "C" void kernel_launch(void* const* d_in, const int* in_sizes, int n_in,
                              void* d_out, int out_size, void* d_ws, size_t ws_size,
                              hipStream_t stream) {
    const float* x = (const float*)d_in[0];
    float* y = (float*)d_out;
    int B = in_sizes[0] / 1024;
    expm32_v4<<<B, 64, 0, stream>>>(x, y);
}